// Round 10
// baseline (745.118 us; speedup 1.0000x reference)
//
#include <hip/hip_runtime.h>
#include <math.h>

namespace {

constexpr int BATCH = 2;
constexpr int H = 1080;
constexpr int W = 1920;
constexpr int HW = H * W;
constexpr int PL = BATCH * HW;          // elements per channel-plane (all batches)
constexpr int NTH = 256;

// ---------------- conv tile geometry ----------------
// 128x8 outputs per 256-thread block, 4 px per thread along x.
// LDS halo tile 130x10, row stride padded to 132 (16B-aligned float4 reads).
constexpr int BX = 128;
constexpr int BY = 8;
constexpr int LW = 132;
constexpr int LH = 10;
constexpr int LDSN = LW * LH;           // 1320 floats = 5280 B (16B multiple)
constexpr int NSTG = (LDSN + NTH - 1) / NTH;   // 6 staging slots/thread

// ---------------- fused box geometry ----------------
constexpr int RMAX = 6;                 // largest radius (K=13)
constexpr int SW_B = 240;               // output columns per block strip
constexpr int COLS = SW_B + 2 * RMAX;   // 252 owned columns (incl. halo)
constexpr int SH_B = 4;                 // 4320 blocks (was 6/2880: more phase
                                        // mixing under the 6-blk/CU LDS cap)

__device__ __forceinline__ float gamma22(float v) {
    return v > 0.f ? exp2f(0.45454545454545453f * log2f(v)) : 0.f;
}

// Fused 3x3 conv, 4 outputs/thread. PAIR-STAGED: one static LDS array,
// channel A at offset 0, channel B at LITERAL offset LDSN (16B-aligned
// constant) -> same proven conflict-free addressing form. 1 barrier pair
// per 2 channels, 1008 FMAs per interval.
// LESSON (x2): indirection over the tile base (runtime-indexed tile[ci&1],
// or array-ref lambda param) kills hipcc's alignment proof -> float4 LDS
// reads split to b32 -> 8-way conflicts (R6: 238us, R8: 491us). All tile
// accesses below are direct on the named static array.
template<int CIN, int COUT, bool GAMMA, bool RELU, bool HEAD>
__global__ __launch_bounds__(NTH) void conv4_k(
        const float* __restrict__ in, const float* __restrict__ wgt,
        const float* __restrict__ bias, float* __restrict__ out)
{
    static_assert(CIN % 2 == 0, "pair staging needs even CIN");
    __shared__ float tile[2 * LDSN];

    const int tx = threadIdx.x & 31;
    const int ty = threadIdx.x >> 5;
    const int x0 = blockIdx.x * BX;
    const int y0 = blockIdx.y * BY;
    const int b  = blockIdx.z;

    float acc[COUT][4];
#pragma unroll
    for (int co = 0; co < COUT; ++co) {
        float bv = bias[co];
#pragma unroll
        for (int p = 0; p < 4; ++p) acc[co][p] = bv;
    }

    float rgA[NSTG], rgB[NSTG];

    auto stage_loadA = [&](int ci) {
#pragma unroll
        for (int s = 0; s < NSTG; ++s) {
            int i = threadIdx.x + s * NTH;
            float v = 0.f;
            if (i < LDSN) {
                int r = i / LW, c = i - r * LW;
                int gy = y0 + r - 1, gx = x0 + c - 1;
                if (c < 130 && gy >= 0 && gy < H && gx >= 0 && gx < W) {
                    if (GAMMA) {
                        if (ci < 3) {
                            float a  = in[((size_t)b * 10 + ci) * HW + (size_t)gy * W + gx];
                            float al = in[((size_t)b * 10 + ci + 3) * HW + (size_t)gy * W + gx];
                            v = gamma22(a * al);
                        } else {
                            v = in[((size_t)b * 10 + ci) * HW + (size_t)gy * W + gx];
                        }
                    } else {
                        v = in[(size_t)ci * PL + (size_t)b * HW + (size_t)gy * W + gx];
                    }
                }
            }
            rgA[s] = v;
        }
    };
    auto stage_loadB = [&](int ci) {
#pragma unroll
        for (int s = 0; s < NSTG; ++s) {
            int i = threadIdx.x + s * NTH;
            float v = 0.f;
            if (i < LDSN) {
                int r = i / LW, c = i - r * LW;
                int gy = y0 + r - 1, gx = x0 + c - 1;
                if (c < 130 && gy >= 0 && gy < H && gx >= 0 && gx < W) {
                    if (GAMMA) {
                        if (ci < 3) {
                            float a  = in[((size_t)b * 10 + ci) * HW + (size_t)gy * W + gx];
                            float al = in[((size_t)b * 10 + ci + 3) * HW + (size_t)gy * W + gx];
                            v = gamma22(a * al);
                        } else {
                            v = in[((size_t)b * 10 + ci) * HW + (size_t)gy * W + gx];
                        }
                    } else {
                        v = in[(size_t)ci * PL + (size_t)b * HW + (size_t)gy * W + gx];
                    }
                }
            }
            rgB[s] = v;
        }
    };

    stage_loadA(0);
    stage_loadB(1);

    constexpr int NPAIR = CIN / 2;
    for (int cp = 0; cp < NPAIR; ++cp) {
        __syncthreads();                 // prior reads of both halves done
#pragma unroll
        for (int s = 0; s < NSTG; ++s) {
            int i = threadIdx.x + s * NTH;
            if (i < LDSN) { tile[i] = rgA[s]; tile[LDSN + i] = rgB[s]; }
        }
        __syncthreads();                 // tiles ready

        if (cp + 1 < NPAIR) {            // next pair in flight across 1008 FMAs
            stage_loadA(2 * cp + 2);
            stage_loadB(2 * cp + 3);
        }

        // ---- channel A (offset 0) ----
        {
            const int ci = 2 * cp;
            float v[3][6];
#pragma unroll
            for (int ky = 0; ky < 3; ++ky) {
                int row = (ty + ky) * LW + tx * 4;
                float4 vA = *reinterpret_cast<const float4*>(&tile[row]);
                float4 vB = *reinterpret_cast<const float4*>(&tile[row + 4]);
                v[ky][0] = vA.x; v[ky][1] = vA.y; v[ky][2] = vA.z; v[ky][3] = vA.w;
                v[ky][4] = vB.x; v[ky][5] = vB.y;
            }
#pragma unroll
            for (int ky = 0; ky < 3; ++ky) {
#pragma unroll
                for (int kx = 0; kx < 3; ++kx) {
#pragma unroll
                    for (int co = 0; co < COUT; ++co) {
                        float w = wgt[(co * CIN + ci) * 9 + ky * 3 + kx];
#pragma unroll
                        for (int p = 0; p < 4; ++p)
                            acc[co][p] = fmaf(v[ky][p + kx], w, acc[co][p]);
                    }
                }
            }
        }
        // ---- channel B (literal offset LDSN) ----
        {
            const int ci = 2 * cp + 1;
            float v[3][6];
#pragma unroll
            for (int ky = 0; ky < 3; ++ky) {
                int row = (ty + ky) * LW + tx * 4;
                float4 vA = *reinterpret_cast<const float4*>(&tile[LDSN + row]);
                float4 vB = *reinterpret_cast<const float4*>(&tile[LDSN + row + 4]);
                v[ky][0] = vA.x; v[ky][1] = vA.y; v[ky][2] = vA.z; v[ky][3] = vA.w;
                v[ky][4] = vB.x; v[ky][5] = vB.y;
            }
#pragma unroll
            for (int ky = 0; ky < 3; ++ky) {
#pragma unroll
                for (int kx = 0; kx < 3; ++kx) {
#pragma unroll
                    for (int co = 0; co < COUT; ++co) {
                        float w = wgt[(co * CIN + ci) * 9 + ky * 3 + kx];
#pragma unroll
                        for (int p = 0; p < 4; ++p)
                            acc[co][p] = fmaf(v[ky][p + kx], w, acc[co][p]);
                    }
                }
            }
        }
    }

    const int y = y0 + ty;
    const size_t obase = (size_t)b * HW + (size_t)y * W + x0 + tx * 4;

    if (HEAD) {
#pragma unroll
        for (int p = 0; p < 4; ++p) {
#pragma unroll
            for (int c = 0; c < 6; ++c)
                out[(size_t)c * PL + obase + p] = expf(acc[c][p]);
            float m = acc[6][p];
#pragma unroll
            for (int c = 7; c < 12; ++c) m = fmaxf(m, acc[c][p]);
            float e[6]; float s = 0.f;
#pragma unroll
            for (int c = 0; c < 6; ++c) { e[c] = expf(acc[6 + c][p] - m); s += e[c]; }
            float inv = 1.f / s;
#pragma unroll
            for (int c = 0; c < 6; ++c)
                out[(size_t)(6 + c) * PL + obase + p] = e[c] * inv;
        }
    } else {
#pragma unroll
        for (int co = 0; co < COUT; ++co) {
            float4 r;
            r.x = RELU ? fmaxf(acc[co][0], 0.f) : acc[co][0];
            r.y = RELU ? fmaxf(acc[co][1], 0.f) : acc[co][1];
            r.z = RELU ? fmaxf(acc[co][2], 0.f) : acc[co][2];
            r.w = RELU ? fmaxf(acc[co][3], 0.f) : acc[co][3];
            *reinterpret_cast<float4*>(&out[(size_t)co * PL + obase]) = r;
        }
    }
}

// All 6 guided-box scales fused. One thread owns one column; 24 sliding
// vertical sums in registers; per output row the v-sums go to LDS as float4
// per (scale,column); horizontal taps are lane-contiguous ds_read_b128.
__global__ __launch_bounds__(NTH) void box_all_k(
        const float* __restrict__ ga, const float* __restrict__ xin,
        float* __restrict__ outp)
{
    __shared__ float4 vls4[6 * NTH];    // [scale][column] -> 24 KB

    const int t  = threadIdx.x;
    const int x0 = blockIdx.x * SW_B;
    const int y0 = blockIdx.y * SH_B;
    const int b  = blockIdx.z;
    const int x  = x0 - RMAX + t;

    const bool tok = t < COLS;                    // owns a column slot
    const bool xok = tok && x >= 0 && x < W;      // column inside image
    const bool ook = t >= RMAX && t < RMAX + SW_B;

    const float* gb = ga + (size_t)b * HW;                 // + i*PL + y*W + x
    const float* xb = xin + (size_t)b * 10 * HW;           // + c*HW + y*W + x

    float vs[6][4];
#pragma unroll
    for (int i = 0; i < 6; ++i)
#pragma unroll
        for (int c = 0; c < 4; ++c) vs[i][c] = 0.f;

    // ---- prime vertical sums for output row y0 ----
#pragma unroll
    for (int r = -RMAX; r <= RMAX; ++r) {
        int yy = y0 + r;
        float g[6], ir[3];
        if (xok && yy >= 0 && yy < H) {
            size_t ro = (size_t)yy * W + x;
#pragma unroll
            for (int i = 0; i < 6; ++i) g[i] = gb[(size_t)i * PL + ro];
#pragma unroll
            for (int c = 0; c < 3; ++c) ir[c] = xb[(size_t)c * HW + ro];
        } else {
#pragma unroll
            for (int i = 0; i < 6; ++i) g[i] = 0.f;
#pragma unroll
            for (int c = 0; c < 3; ++c) ir[c] = 0.f;
        }
#pragma unroll
        for (int i = 0; i < 6; ++i) {
            if (r >= -(i + 1) && r <= (i + 1)) {   // compile-time folded
                vs[i][0] += g[i];
                vs[i][1] = fmaf(g[i], ir[0], vs[i][1]);
                vs[i][2] = fmaf(g[i], ir[1], vs[i][2]);
                vs[i][3] = fmaf(g[i], ir[2], vs[i][3]);
            }
        }
    }

    // ---- main row loop ----
    for (int dy = 0; dy < SH_B; ++dy) {
        const int y = y0 + dy;
        const size_t ro = (size_t)y * W + x;

        // preload alpha/alb for this row before the barrier (overlaps wait)
        float al[6], ab[3];
        if (ook) {
#pragma unroll
            for (int i = 0; i < 6; ++i) al[i] = gb[(size_t)(6 + i) * PL + ro];
#pragma unroll
            for (int c = 0; c < 3; ++c) ab[c] = xb[(size_t)(3 + c) * HW + ro];
        }

        if (tok) {
#pragma unroll
            for (int i = 0; i < 6; ++i)
                vls4[i * NTH + t] = make_float4(vs[i][0], vs[i][1], vs[i][2], vs[i][3]);
        }
        __syncthreads();

        // ---- slide vs to row y+1 now: vs is dead until next LDS write,
        // so these loads fly while the h-pass below computes ----
        if (dy + 1 < SH_B && xok) {
#pragma unroll
            for (int i = 0; i < 6; ++i) {
                const int R = i + 1;
                int ya = y + 1 + R;            // entering row
                int yr = y - R;                // leaving row
                if (ya < H) {
                    size_t r2 = (size_t)ya * W + x;
                    float g = gb[(size_t)i * PL + r2];
                    vs[i][0] += g;
                    vs[i][1] = fmaf(g, xb[r2], vs[i][1]);
                    vs[i][2] = fmaf(g, xb[(size_t)HW + r2], vs[i][2]);
                    vs[i][3] = fmaf(g, xb[(size_t)2 * HW + r2], vs[i][3]);
                }
                if (yr >= 0) {
                    size_t r2 = (size_t)yr * W + x;
                    float g = gb[(size_t)i * PL + r2];
                    vs[i][0] -= g;
                    vs[i][1] = fmaf(-g, xb[r2], vs[i][1]);
                    vs[i][2] = fmaf(-g, xb[(size_t)HW + r2], vs[i][2]);
                    vs[i][3] = fmaf(-g, xb[(size_t)2 * HW + r2], vs[i][3]);
                }
            }
        }

        if (ook) {
            float o0 = 0.f, o1 = 0.f, o2 = 0.f;
#pragma unroll
            for (int i = 0; i < 6; ++i) {
                const int R = i + 1;
                float sw = 0.f, s0 = 0.f, s1 = 0.f, s2 = 0.f;
#pragma unroll
                for (int dx = -R; dx <= R; ++dx) {
                    float4 v = vls4[i * NTH + t + dx];
                    sw += v.x; s0 += v.y; s1 += v.z; s2 += v.w;
                }
                float rw = al[i] / sw;
                o0 = fmaf(s0, rw, o0);
                o1 = fmaf(s1, rw, o1);
                o2 = fmaf(s2, rw, o2);
            }
            size_t o = (size_t)b * 3 * HW + ro;
            outp[o]                  = o0 * ab[0];
            outp[o + HW]             = o1 * ab[1];
            outp[o + (size_t)2 * HW] = o2 * ab[2];
        }
        __syncthreads();    // h-pass LDS reads done before next row's writes
    }
}

} // namespace

extern "C" void kernel_launch(void* const* d_in, const int* in_sizes, int n_in,
                              void* d_out, int out_size, void* d_ws, size_t ws_size,
                              hipStream_t stream)
{
    const float* xin = (const float*)d_in[0];
    const float* W1p = (const float*)d_in[1];
    const float* b1p = (const float*)d_in[2];
    const float* W2p = (const float*)d_in[3];
    const float* b2p = (const float*)d_in[4];
    const float* W3p = (const float*)d_in[5];
    const float* b3p = (const float*)d_in[6];
    float* outp = (float*)d_out;
    float* ws = (float*)d_ws;

    // ws layout (28 planes of PL floats):
    //   h1 : planes  0..13 ; h2 : planes 14..27 ; ga : planes 0..11 (reuses h1)
    float* h1 = ws;
    float* h2 = ws + (size_t)14 * PL;
    float* ga = ws;

    dim3 blk(NTH);
    dim3 cgrid(W / BX, H / BY, BATCH);
    dim3 bgrid(W / SW_B, H / SH_B, BATCH);

    conv4_k<10, 14, true,  true,  false><<<cgrid, blk, 0, stream>>>(xin, W1p, b1p, h1);
    conv4_k<14, 14, false, true,  false><<<cgrid, blk, 0, stream>>>(h1,  W2p, b2p, h2);
    conv4_k<14, 12, false, false, true ><<<cgrid, blk, 0, stream>>>(h2,  W3p, b3p, ga);

    box_all_k<<<bgrid, blk, 0, stream>>>(ga, xin, outp);
}

// Round 11
// 662.724 us; speedup vs baseline: 1.1243x; 1.1243x over previous
//
#include <hip/hip_runtime.h>
#include <math.h>

namespace {

constexpr int BATCH = 2;
constexpr int H = 1080;
constexpr int W = 1920;
constexpr int HW = H * W;
constexpr int PL = BATCH * HW;          // elements per channel-plane (all batches)
constexpr int NTH = 256;

// ---------------- conv tile geometry ----------------
// 128x8 outputs per 256-thread block, 4 px per thread along x.
// LDS halo tile 130x10, row stride padded to 132 (16B-aligned float4 reads).
constexpr int BX = 128;
constexpr int BY = 8;
constexpr int LW = 132;
constexpr int LH = 10;
constexpr int LDSN = LW * LH;           // 1320 floats
constexpr int NSTG = (LDSN + NTH - 1) / NTH;   // 6 staging slots/thread

// ---------------- fused box geometry ----------------
constexpr int RMAX = 6;                 // largest radius (K=13)
constexpr int SW_B = 240;               // output columns per block strip
constexpr int COLS = SW_B + 2 * RMAX;   // 252 owned columns (incl. halo)
constexpr int SH_B = 4;                 // 4320 blocks: box ~97us (vs 212 @SH_B=6)

__device__ __forceinline__ float gamma22(float v) {
    return v > 0.f ? exp2f(0.45454545454545453f * log2f(v)) : 0.f;
}

// Fused 3x3 conv, 4 outputs/thread. FROZEN R5 structure (measured 156us,
// ~0 LDS conflicts). RULE after three failed variants (R6 runtime-indexed
// base / R8 array-ref param / R10 second region at literal offset in one
// array -- ALL regressed to 216-491us with 4-16e6 bank conflicts): hipcc
// only keeps the b128 LDS vectorization + conflict-free addressing for
// EXACTLY this form -- single static tile[LDSN], direct name access,
// 2 barriers per channel. Do not restructure the conv LDS schedule.
template<int CIN, int COUT, bool GAMMA, bool RELU, bool HEAD>
__global__ __launch_bounds__(NTH) void conv4_k(
        const float* __restrict__ in, const float* __restrict__ wgt,
        const float* __restrict__ bias, float* __restrict__ out)
{
    __shared__ float tile[LDSN];

    const int tx = threadIdx.x & 31;
    const int ty = threadIdx.x >> 5;
    const int x0 = blockIdx.x * BX;
    const int y0 = blockIdx.y * BY;
    const int b  = blockIdx.z;

    float acc[COUT][4];
#pragma unroll
    for (int co = 0; co < COUT; ++co) {
        float bv = bias[co];
#pragma unroll
        for (int p = 0; p < 4; ++p) acc[co][p] = bv;
    }

    float rg[NSTG];

    auto stage_load = [&](int ci) {
#pragma unroll
        for (int s = 0; s < NSTG; ++s) {
            int i = threadIdx.x + s * NTH;
            float v = 0.f;
            if (i < LDSN) {
                int r = i / LW, c = i - r * LW;
                int gy = y0 + r - 1, gx = x0 + c - 1;
                if (c < 130 && gy >= 0 && gy < H && gx >= 0 && gx < W) {
                    if (GAMMA) {
                        if (ci < 3) {
                            float a  = in[((size_t)b * 10 + ci) * HW + (size_t)gy * W + gx];
                            float al = in[((size_t)b * 10 + ci + 3) * HW + (size_t)gy * W + gx];
                            v = gamma22(a * al);
                        } else {
                            v = in[((size_t)b * 10 + ci) * HW + (size_t)gy * W + gx];
                        }
                    } else {
                        v = in[(size_t)ci * PL + (size_t)b * HW + (size_t)gy * W + gx];
                    }
                }
            }
            rg[s] = v;
        }
    };

    stage_load(0);

    for (int ci = 0; ci < CIN; ++ci) {
        __syncthreads();
#pragma unroll
        for (int s = 0; s < NSTG; ++s) {
            int i = threadIdx.x + s * NTH;
            if (i < LDSN) tile[i] = rg[s];
        }
        __syncthreads();

        if (ci + 1 < CIN) stage_load(ci + 1);   // hide loads under FMAs

        // 6-col window per row via TWO aligned float4 reads (lane-contiguous
        // b128 = conflict-free LDS pattern); tile addressed by static name
        float v[3][6];
#pragma unroll
        for (int ky = 0; ky < 3; ++ky) {
            int row = (ty + ky) * LW + tx * 4;
            float4 vA = *reinterpret_cast<const float4*>(&tile[row]);
            float4 vB = *reinterpret_cast<const float4*>(&tile[row + 4]);
            v[ky][0] = vA.x; v[ky][1] = vA.y; v[ky][2] = vA.z; v[ky][3] = vA.w;
            v[ky][4] = vB.x; v[ky][5] = vB.y;
        }

#pragma unroll
        for (int ky = 0; ky < 3; ++ky) {
#pragma unroll
            for (int kx = 0; kx < 3; ++kx) {
#pragma unroll
                for (int co = 0; co < COUT; ++co) {
                    float w = wgt[(co * CIN + ci) * 9 + ky * 3 + kx];
#pragma unroll
                    for (int p = 0; p < 4; ++p)
                        acc[co][p] = fmaf(v[ky][p + kx], w, acc[co][p]);
                }
            }
        }
    }

    const int y = y0 + ty;
    const size_t obase = (size_t)b * HW + (size_t)y * W + x0 + tx * 4;

    if (HEAD) {
#pragma unroll
        for (int p = 0; p < 4; ++p) {
#pragma unroll
            for (int c = 0; c < 6; ++c)
                out[(size_t)c * PL + obase + p] = expf(acc[c][p]);
            float m = acc[6][p];
#pragma unroll
            for (int c = 7; c < 12; ++c) m = fmaxf(m, acc[c][p]);
            float e[6]; float s = 0.f;
#pragma unroll
            for (int c = 0; c < 6; ++c) { e[c] = expf(acc[6 + c][p] - m); s += e[c]; }
            float inv = 1.f / s;
#pragma unroll
            for (int c = 0; c < 6; ++c)
                out[(size_t)(6 + c) * PL + obase + p] = e[c] * inv;
        }
    } else {
#pragma unroll
        for (int co = 0; co < COUT; ++co) {
            float4 r;
            r.x = RELU ? fmaxf(acc[co][0], 0.f) : acc[co][0];
            r.y = RELU ? fmaxf(acc[co][1], 0.f) : acc[co][1];
            r.z = RELU ? fmaxf(acc[co][2], 0.f) : acc[co][2];
            r.w = RELU ? fmaxf(acc[co][3], 0.f) : acc[co][3];
            *reinterpret_cast<float4*>(&out[(size_t)co * PL + obase]) = r;
        }
    }
}

// All 6 guided-box scales fused. One thread owns one column; 24 sliding
// vertical sums in registers; per output row the v-sums go to LDS as float4
// per (scale,column); horizontal taps are lane-contiguous ds_read_b128.
// SH_B=4: short-lived blocks phase-mix prime/stream under the 6-blk/CU
// LDS cap -> measured ~97us (212 @SH_B=6, 820 @SH_B=72).
__global__ __launch_bounds__(NTH) void box_all_k(
        const float* __restrict__ ga, const float* __restrict__ xin,
        float* __restrict__ outp)
{
    __shared__ float4 vls4[6 * NTH];    // [scale][column] -> 24 KB

    const int t  = threadIdx.x;
    const int x0 = blockIdx.x * SW_B;
    const int y0 = blockIdx.y * SH_B;
    const int b  = blockIdx.z;
    const int x  = x0 - RMAX + t;

    const bool tok = t < COLS;                    // owns a column slot
    const bool xok = tok && x >= 0 && x < W;      // column inside image
    const bool ook = t >= RMAX && t < RMAX + SW_B;

    const float* gb = ga + (size_t)b * HW;                 // + i*PL + y*W + x
    const float* xb = xin + (size_t)b * 10 * HW;           // + c*HW + y*W + x

    float vs[6][4];
#pragma unroll
    for (int i = 0; i < 6; ++i)
#pragma unroll
        for (int c = 0; c < 4; ++c) vs[i][c] = 0.f;

    // ---- prime vertical sums for output row y0 ----
#pragma unroll
    for (int r = -RMAX; r <= RMAX; ++r) {
        int yy = y0 + r;
        float g[6], ir[3];
        if (xok && yy >= 0 && yy < H) {
            size_t ro = (size_t)yy * W + x;
#pragma unroll
            for (int i = 0; i < 6; ++i) g[i] = gb[(size_t)i * PL + ro];
#pragma unroll
            for (int c = 0; c < 3; ++c) ir[c] = xb[(size_t)c * HW + ro];
        } else {
#pragma unroll
            for (int i = 0; i < 6; ++i) g[i] = 0.f;
#pragma unroll
            for (int c = 0; c < 3; ++c) ir[c] = 0.f;
        }
#pragma unroll
        for (int i = 0; i < 6; ++i) {
            if (r >= -(i + 1) && r <= (i + 1)) {   // compile-time folded
                vs[i][0] += g[i];
                vs[i][1] = fmaf(g[i], ir[0], vs[i][1]);
                vs[i][2] = fmaf(g[i], ir[1], vs[i][2]);
                vs[i][3] = fmaf(g[i], ir[2], vs[i][3]);
            }
        }
    }

    // ---- main row loop ----
    for (int dy = 0; dy < SH_B; ++dy) {
        const int y = y0 + dy;
        const size_t ro = (size_t)y * W + x;

        // preload alpha/alb for this row before the barrier (overlaps wait)
        float al[6], ab[3];
        if (ook) {
#pragma unroll
            for (int i = 0; i < 6; ++i) al[i] = gb[(size_t)(6 + i) * PL + ro];
#pragma unroll
            for (int c = 0; c < 3; ++c) ab[c] = xb[(size_t)(3 + c) * HW + ro];
        }

        if (tok) {
#pragma unroll
            for (int i = 0; i < 6; ++i)
                vls4[i * NTH + t] = make_float4(vs[i][0], vs[i][1], vs[i][2], vs[i][3]);
        }
        __syncthreads();

        // ---- slide vs to row y+1 now: vs is dead until next LDS write,
        // so these loads fly while the h-pass below computes ----
        if (dy + 1 < SH_B && xok) {
#pragma unroll
            for (int i = 0; i < 6; ++i) {
                const int R = i + 1;
                int ya = y + 1 + R;            // entering row
                int yr = y - R;                // leaving row
                if (ya < H) {
                    size_t r2 = (size_t)ya * W + x;
                    float g = gb[(size_t)i * PL + r2];
                    vs[i][0] += g;
                    vs[i][1] = fmaf(g, xb[r2], vs[i][1]);
                    vs[i][2] = fmaf(g, xb[(size_t)HW + r2], vs[i][2]);
                    vs[i][3] = fmaf(g, xb[(size_t)2 * HW + r2], vs[i][3]);
                }
                if (yr >= 0) {
                    size_t r2 = (size_t)yr * W + x;
                    float g = gb[(size_t)i * PL + r2];
                    vs[i][0] -= g;
                    vs[i][1] = fmaf(-g, xb[r2], vs[i][1]);
                    vs[i][2] = fmaf(-g, xb[(size_t)HW + r2], vs[i][2]);
                    vs[i][3] = fmaf(-g, xb[(size_t)2 * HW + r2], vs[i][3]);
                }
            }
        }

        if (ook) {
            float o0 = 0.f, o1 = 0.f, o2 = 0.f;
#pragma unroll
            for (int i = 0; i < 6; ++i) {
                const int R = i + 1;
                float sw = 0.f, s0 = 0.f, s1 = 0.f, s2 = 0.f;
#pragma unroll
                for (int dx = -R; dx <= R; ++dx) {
                    float4 v = vls4[i * NTH + t + dx];
                    sw += v.x; s0 += v.y; s1 += v.z; s2 += v.w;
                }
                float rw = al[i] / sw;
                o0 = fmaf(s0, rw, o0);
                o1 = fmaf(s1, rw, o1);
                o2 = fmaf(s2, rw, o2);
            }
            size_t o = (size_t)b * 3 * HW + ro;
            outp[o]                  = o0 * ab[0];
            outp[o + HW]             = o1 * ab[1];
            outp[o + (size_t)2 * HW] = o2 * ab[2];
        }
        __syncthreads();    // h-pass LDS reads done before next row's writes
    }
}

} // namespace

extern "C" void kernel_launch(void* const* d_in, const int* in_sizes, int n_in,
                              void* d_out, int out_size, void* d_ws, size_t ws_size,
                              hipStream_t stream)
{
    const float* xin = (const float*)d_in[0];
    const float* W1p = (const float*)d_in[1];
    const float* b1p = (const float*)d_in[2];
    const float* W2p = (const float*)d_in[3];
    const float* b2p = (const float*)d_in[4];
    const float* W3p = (const float*)d_in[5];
    const float* b3p = (const float*)d_in[6];
    float* outp = (float*)d_out;
    float* ws = (float*)d_ws;

    // ws layout (28 planes of PL floats):
    //   h1 : planes  0..13 ; h2 : planes 14..27 ; ga : planes 0..11 (reuses h1)
    float* h1 = ws;
    float* h2 = ws + (size_t)14 * PL;
    float* ga = ws;

    dim3 blk(NTH);
    dim3 cgrid(W / BX, H / BY, BATCH);
    dim3 bgrid(W / SW_B, H / SH_B, BATCH);

    conv4_k<10, 14, true,  true,  false><<<cgrid, blk, 0, stream>>>(xin, W1p, b1p, h1);
    conv4_k<14, 14, false, true,  false><<<cgrid, blk, 0, stream>>>(h1,  W2p, b2p, h2);
    conv4_k<14, 12, false, false, true ><<<cgrid, blk, 0, stream>>>(h2,  W3p, b3p, ga);

    box_all_k<<<bgrid, blk, 0, stream>>>(ga, xin, outp);
}

// Round 14
// 660.153 us; speedup vs baseline: 1.1287x; 1.0039x over previous
//
#include <hip/hip_runtime.h>
#include <math.h>

namespace {

constexpr int BATCH = 2;
constexpr int H = 1080;
constexpr int W = 1920;
constexpr int HW = H * W;
constexpr int PL = BATCH * HW;          // elements per channel-plane (all batches)
constexpr int NTH = 256;

// ---------------- conv tile geometry ----------------
// 128x8 outputs per 256-thread block, 4 px per thread along x.
// LDS halo tile 130x10, row stride padded to 132 (16B-aligned float4 reads).
constexpr int BX = 128;
constexpr int BY = 8;
constexpr int LW = 132;
constexpr int LH = 10;
constexpr int LDSN = LW * LH;           // 1320 floats
constexpr int NSTG = (LDSN + NTH - 1) / NTH;   // 6 staging slots/thread

// ---------------- fused box geometry ----------------
constexpr int RMAX = 6;                 // largest radius (K=13)
constexpr int SW_B = 240;               // output columns per block strip
constexpr int COLS = SW_B + 2 * RMAX;   // 252 owned columns (incl. halo)
constexpr int SH_B = 4;                 // 4320 blocks: measured 191us

__device__ __forceinline__ float gamma22(float v) {
    return v > 0.f ? exp2f(0.45454545454545453f * log2f(v)) : 0.f;
}

// Fused 3x3 conv, 4 outputs/thread. FROZEN R5 structure (measured ~157us,
// ~0 LDS conflicts). RULE after three failed variants (R6 runtime-indexed
// base / R8 array-ref param / R10 second region at literal offset): hipcc
// only keeps b128 LDS vectorization + conflict-free addressing for EXACTLY
// this form -- single static tile[LDSN], direct name access, 2 barriers
// per channel. Do not restructure the conv LDS schedule.
template<int CIN, int COUT, bool GAMMA, bool RELU, bool HEAD>
__global__ __launch_bounds__(NTH) void conv4_k(
        const float* __restrict__ in, const float* __restrict__ wgt,
        const float* __restrict__ bias, float* __restrict__ out)
{
    __shared__ float tile[LDSN];

    const int tx = threadIdx.x & 31;
    const int ty = threadIdx.x >> 5;
    const int x0 = blockIdx.x * BX;
    const int y0 = blockIdx.y * BY;
    const int b  = blockIdx.z;

    float acc[COUT][4];
#pragma unroll
    for (int co = 0; co < COUT; ++co) {
        float bv = bias[co];
#pragma unroll
        for (int p = 0; p < 4; ++p) acc[co][p] = bv;
    }

    float rg[NSTG];

    auto stage_load = [&](int ci) {
#pragma unroll
        for (int s = 0; s < NSTG; ++s) {
            int i = threadIdx.x + s * NTH;
            float v = 0.f;
            if (i < LDSN) {
                int r = i / LW, c = i - r * LW;
                int gy = y0 + r - 1, gx = x0 + c - 1;
                if (c < 130 && gy >= 0 && gy < H && gx >= 0 && gx < W) {
                    if (GAMMA) {
                        if (ci < 3) {
                            float a  = in[((size_t)b * 10 + ci) * HW + (size_t)gy * W + gx];
                            float al = in[((size_t)b * 10 + ci + 3) * HW + (size_t)gy * W + gx];
                            v = gamma22(a * al);
                        } else {
                            v = in[((size_t)b * 10 + ci) * HW + (size_t)gy * W + gx];
                        }
                    } else {
                        v = in[(size_t)ci * PL + (size_t)b * HW + (size_t)gy * W + gx];
                    }
                }
            }
            rg[s] = v;
        }
    };

    stage_load(0);

    for (int ci = 0; ci < CIN; ++ci) {
        __syncthreads();
#pragma unroll
        for (int s = 0; s < NSTG; ++s) {
            int i = threadIdx.x + s * NTH;
            if (i < LDSN) tile[i] = rg[s];
        }
        __syncthreads();

        if (ci + 1 < CIN) stage_load(ci + 1);   // hide loads under FMAs

        // 6-col window per row via TWO aligned float4 reads (lane-contiguous
        // b128 = conflict-free LDS pattern); tile addressed by static name
        float v[3][6];
#pragma unroll
        for (int ky = 0; ky < 3; ++ky) {
            int row = (ty + ky) * LW + tx * 4;
            float4 vA = *reinterpret_cast<const float4*>(&tile[row]);
            float4 vB = *reinterpret_cast<const float4*>(&tile[row + 4]);
            v[ky][0] = vA.x; v[ky][1] = vA.y; v[ky][2] = vA.z; v[ky][3] = vA.w;
            v[ky][4] = vB.x; v[ky][5] = vB.y;
        }

#pragma unroll
        for (int ky = 0; ky < 3; ++ky) {
#pragma unroll
            for (int kx = 0; kx < 3; ++kx) {
#pragma unroll
                for (int co = 0; co < COUT; ++co) {
                    float w = wgt[(co * CIN + ci) * 9 + ky * 3 + kx];
#pragma unroll
                    for (int p = 0; p < 4; ++p)
                        acc[co][p] = fmaf(v[ky][p + kx], w, acc[co][p]);
                }
            }
        }
    }

    const int y = y0 + ty;
    const size_t obase = (size_t)b * HW + (size_t)y * W + x0 + tx * 4;

    if (HEAD) {
#pragma unroll
        for (int p = 0; p < 4; ++p) {
#pragma unroll
            for (int c = 0; c < 6; ++c)
                out[(size_t)c * PL + obase + p] = expf(acc[c][p]);
            float m = acc[6][p];
#pragma unroll
            for (int c = 7; c < 12; ++c) m = fmaxf(m, acc[c][p]);
            float e[6]; float s = 0.f;
#pragma unroll
            for (int c = 0; c < 6; ++c) { e[c] = expf(acc[6 + c][p] - m); s += e[c]; }
            float inv = 1.f / s;
#pragma unroll
            for (int c = 0; c < 6; ++c)
                out[(size_t)(6 + c) * PL + obase + p] = e[c] * inv;
        }
    } else {
#pragma unroll
        for (int co = 0; co < COUT; ++co) {
            float4 r;
            r.x = RELU ? fmaxf(acc[co][0], 0.f) : acc[co][0];
            r.y = RELU ? fmaxf(acc[co][1], 0.f) : acc[co][1];
            r.z = RELU ? fmaxf(acc[co][2], 0.f) : acc[co][2];
            r.w = RELU ? fmaxf(acc[co][3], 0.f) : acc[co][3];
            *reinterpret_cast<float4*>(&out[(size_t)co * PL + obase]) = r;
        }
    }
}

// All 6 guided-box scales fused (PROVEN R11 form, measured 191us, full
// timing pass). One 256-thread block owns a 240-column strip; 24 sliding
// vertical sums in registers; per output row v-sums go to LDS as float4
// per (scale,column); horizontal taps are lane-contiguous ds_read_b128.
// R12/R13 LESSON: the single-wave (64-thread) variant of this kernel
// failed nondeterministically post-timing (suspected single-wave s_barrier
// elision + LDS reorder). Keep 4-wave blocks with real barriers.
__global__ __launch_bounds__(NTH) void box_all_k(
        const float* __restrict__ ga, const float* __restrict__ xin,
        float* __restrict__ outp)
{
    __shared__ float4 vls4[6 * NTH];    // [scale][column] -> 24 KB

    const int t  = threadIdx.x;
    const int x0 = blockIdx.x * SW_B;
    const int y0 = blockIdx.y * SH_B;
    const int b  = blockIdx.z;
    const int x  = x0 - RMAX + t;

    const bool tok = t < COLS;                    // owns a column slot
    const bool xok = tok && x >= 0 && x < W;      // column inside image
    const bool ook = t >= RMAX && t < RMAX + SW_B;

    const float* gb = ga + (size_t)b * HW;                 // + i*PL + y*W + x
    const float* xb = xin + (size_t)b * 10 * HW;           // + c*HW + y*W + x

    float vs[6][4];
#pragma unroll
    for (int i = 0; i < 6; ++i)
#pragma unroll
        for (int c = 0; c < 4; ++c) vs[i][c] = 0.f;

    // ---- prime vertical sums for output row y0 ----
#pragma unroll
    for (int r = -RMAX; r <= RMAX; ++r) {
        int yy = y0 + r;
        float g[6], ir[3];
        if (xok && yy >= 0 && yy < H) {
            size_t ro = (size_t)yy * W + x;
#pragma unroll
            for (int i = 0; i < 6; ++i) g[i] = gb[(size_t)i * PL + ro];
#pragma unroll
            for (int c = 0; c < 3; ++c) ir[c] = xb[(size_t)c * HW + ro];
        } else {
#pragma unroll
            for (int i = 0; i < 6; ++i) g[i] = 0.f;
#pragma unroll
            for (int c = 0; c < 3; ++c) ir[c] = 0.f;
        }
#pragma unroll
        for (int i = 0; i < 6; ++i) {
            if (r >= -(i + 1) && r <= (i + 1)) {   // compile-time folded
                vs[i][0] += g[i];
                vs[i][1] = fmaf(g[i], ir[0], vs[i][1]);
                vs[i][2] = fmaf(g[i], ir[1], vs[i][2]);
                vs[i][3] = fmaf(g[i], ir[2], vs[i][3]);
            }
        }
    }

    // ---- main row loop ----
    for (int dy = 0; dy < SH_B; ++dy) {
        const int y = y0 + dy;
        const size_t ro = (size_t)y * W + x;

        // preload alpha/alb for this row before the barrier (overlaps wait)
        float al[6], ab[3];
        if (ook) {
#pragma unroll
            for (int i = 0; i < 6; ++i) al[i] = gb[(size_t)(6 + i) * PL + ro];
#pragma unroll
            for (int c = 0; c < 3; ++c) ab[c] = xb[(size_t)(3 + c) * HW + ro];
        }

        if (tok) {
#pragma unroll
            for (int i = 0; i < 6; ++i)
                vls4[i * NTH + t] = make_float4(vs[i][0], vs[i][1], vs[i][2], vs[i][3]);
        }
        __syncthreads();

        // ---- slide vs to row y+1 now: vs is dead until next LDS write,
        // so these loads fly while the h-pass below computes ----
        if (dy + 1 < SH_B && xok) {
#pragma unroll
            for (int i = 0; i < 6; ++i) {
                const int R = i + 1;
                int ya = y + 1 + R;            // entering row
                int yr = y - R;                // leaving row
                if (ya < H) {
                    size_t r2 = (size_t)ya * W + x;
                    float g = gb[(size_t)i * PL + r2];
                    vs[i][0] += g;
                    vs[i][1] = fmaf(g, xb[r2], vs[i][1]);
                    vs[i][2] = fmaf(g, xb[(size_t)HW + r2], vs[i][2]);
                    vs[i][3] = fmaf(g, xb[(size_t)2 * HW + r2], vs[i][3]);
                }
                if (yr >= 0) {
                    size_t r2 = (size_t)yr * W + x;
                    float g = gb[(size_t)i * PL + r2];
                    vs[i][0] -= g;
                    vs[i][1] = fmaf(-g, xb[r2], vs[i][1]);
                    vs[i][2] = fmaf(-g, xb[(size_t)HW + r2], vs[i][2]);
                    vs[i][3] = fmaf(-g, xb[(size_t)2 * HW + r2], vs[i][3]);
                }
            }
        }

        if (ook) {
            float o0 = 0.f, o1 = 0.f, o2 = 0.f;
#pragma unroll
            for (int i = 0; i < 6; ++i) {
                const int R = i + 1;
                float sw = 0.f, s0 = 0.f, s1 = 0.f, s2 = 0.f;
#pragma unroll
                for (int dx = -R; dx <= R; ++dx) {
                    float4 v = vls4[i * NTH + t + dx];
                    sw += v.x; s0 += v.y; s1 += v.z; s2 += v.w;
                }
                float rw = al[i] / sw;
                o0 = fmaf(s0, rw, o0);
                o1 = fmaf(s1, rw, o1);
                o2 = fmaf(s2, rw, o2);
            }
            size_t o = (size_t)b * 3 * HW + ro;
            outp[o]                  = o0 * ab[0];
            outp[o + HW]             = o1 * ab[1];
            outp[o + (size_t)2 * HW] = o2 * ab[2];
        }
        __syncthreads();    // h-pass LDS reads done before next row's writes
    }
}

} // namespace

extern "C" void kernel_launch(void* const* d_in, const int* in_sizes, int n_in,
                              void* d_out, int out_size, void* d_ws, size_t ws_size,
                              hipStream_t stream)
{
    const float* xin = (const float*)d_in[0];
    const float* W1p = (const float*)d_in[1];
    const float* b1p = (const float*)d_in[2];
    const float* W2p = (const float*)d_in[3];
    const float* b2p = (const float*)d_in[4];
    const float* W3p = (const float*)d_in[5];
    const float* b3p = (const float*)d_in[6];
    float* outp = (float*)d_out;
    float* ws = (float*)d_ws;

    // ws layout (28 planes of PL floats):
    //   h1 : planes  0..13 ; h2 : planes 14..27 ; ga : planes 0..11 (reuses h1)
    float* h1 = ws;
    float* h2 = ws + (size_t)14 * PL;
    float* ga = ws;

    dim3 blk(NTH);
    dim3 cgrid(W / BX, H / BY, BATCH);
    dim3 bgrid(W / SW_B, H / SH_B, BATCH);

    conv4_k<10, 14, true,  true,  false><<<cgrid, blk, 0, stream>>>(xin, W1p, b1p, h1);
    conv4_k<14, 14, false, true,  false><<<cgrid, blk, 0, stream>>>(h1,  W2p, b2p, h2);
    conv4_k<14, 12, false, false, true ><<<cgrid, blk, 0, stream>>>(h2,  W3p, b3p, ga);

    box_all_k<<<bgrid, blk, 0, stream>>>(ga, xin, outp);
}